// Round 12
// baseline (104.984 us; speedup 1.0000x reference)
//
#include <hip/hip_runtime.h>
#include <math.h>

#define B_DIM   4
#define C_DIM   256
#define H_DIM   64
#define W_DIM   64
#define HW_DIM  4096   // H*W
#define NPIX    (B_DIM * HW_DIM)   // 16384
#define NREF    4
#define NJ      10     // 8 offset rows + u (bq^T Wk) + v (bk^T Wq)

typedef unsigned short u16;
typedef __attribute__((ext_vector_type(4))) unsigned short u16x4;
typedef __attribute__((ext_vector_type(8))) unsigned short u16x8;
typedef __attribute__((ext_vector_type(8))) short bf16x8;
typedef __attribute__((ext_vector_type(4))) float f32x4;

__device__ __forceinline__ u16 bf16_rne(float f) {
    unsigned u = __float_as_uint(f);
    u = u + 0x7FFFu + ((u >> 16) & 1u);
    return (u16)(u >> 16);
}
__device__ __forceinline__ float bf16_tof(u16 h) {
    return __uint_as_float(((unsigned)h) << 16);
}
__device__ __forceinline__ void gload16(const void* g, void* l) {
    __builtin_amdgcn_global_load_lds(
        (const __attribute__((address_space(1))) void*)g,
        (__attribute__((address_space(3))) void*)l, 16, 0, 0);
}

// ---------------------------------------------------------------------------
// prep (80 blocks) — unchanged from the passing round-6 kernel:
//  bx<40 : GEMV-row partials Weffp (f64, INDEX PATH)
//  40<=bx<72 : M = Wq^T Wk sub-tile in f32 -> swizzled bf16 hi/lo image
//  bx>=72 : Wv tiles -> swizzled bf16 hi image (tiles 8..15)
// ---------------------------------------------------------------------------
__global__ __launch_bounds__(256) void prep_kernel(
    const float* __restrict__ Wq, const float* __restrict__ bq,
    const float* __restrict__ Wk, const float* __restrict__ bk,
    const float* __restrict__ Wv,
    const float* __restrict__ Woff, const float* __restrict__ boff,
    double* __restrict__ Weffp, double* __restrict__ beff,
    u16* __restrict__ Bswh, u16* __restrict__ Bswl)
{
    const int bx = blockIdx.x;
    const int t  = threadIdx.x;

    if (bx < 4 * NJ) {
        const int j  = bx >> 2;
        const int q  = bx & 3;
        const int o0 = q * 64;
        const float* Avec = (j < 8) ? (Woff + j * C_DIM) : ((j == 8) ? bq : bk);
        const float* Bmat = (j == 8) ? Wk : Wq;
        double s0 = 0, s1 = 0, s2 = 0, s3 = 0;
        for (int o = o0; o < o0 + 64; o += 4) {
            s0 += (double)Avec[o + 0] * (double)Bmat[(size_t)(o + 0) * C_DIM + t];
            s1 += (double)Avec[o + 1] * (double)Bmat[(size_t)(o + 1) * C_DIM + t];
            s2 += (double)Avec[o + 2] * (double)Bmat[(size_t)(o + 2) * C_DIM + t];
            s3 += (double)Avec[o + 3] * (double)Bmat[(size_t)(o + 3) * C_DIM + t];
        }
        Weffp[(size_t)(q * NJ + j) * C_DIM + t] = (s0 + s1) + (s2 + s3);

        if (q == 0 && j <= 8) {
            __shared__ double red[256];
            red[t] = (j < 8) ? (double)Woff[j * C_DIM + t] * (double)bq[t]
                             : (double)bq[t] * (double)bk[t];
            __syncthreads();
            for (int st = 128; st > 0; st >>= 1) {
                if (t < st) red[t] += red[t + st];
                __syncthreads();
            }
            if (t == 0) beff[j] = (j < 8) ? red[0] + (double)boff[j] : red[0];
        }
    } else if (bx < 72) {
        __shared__ float wq_s[64][32];
        __shared__ float wk_s[64][64];
        const int sub   = bx - 40;
        const int T     = sub >> 2;
        const int nsub  = sub & 3;
        const int ntile = T >> 2;
        const int kt    = T & 3;
        const int nb    = ntile * 128 + nsub * 32;
        const int kb    = kt * 64;

        const int tx = t & 15;
        const int ty = t >> 4;

        float acc[2][4] = {};

        for (int oc = 0; oc < 4; ++oc) {
            const int o0 = oc * 64;
#pragma unroll
            for (int i = 0; i < 2; ++i) {
                const int s = i * 256 + t;
                const int row = s >> 3, c4 = (s & 7) * 4;
                *(float4*)&wq_s[row][c4] =
                    *(const float4*)(Wq + (size_t)(o0 + row) * C_DIM + nb + c4);
            }
#pragma unroll
            for (int i = 0; i < 4; ++i) {
                const int s = i * 256 + t;
                const int row = s >> 4, c4 = (s & 15) * 4;
                *(float4*)&wk_s[row][c4] =
                    *(const float4*)(Wk + (size_t)(o0 + row) * C_DIM + kb + c4);
            }
            __syncthreads();
#pragma unroll 4
            for (int oo = 0; oo < 64; ++oo) {
                const float2 a = *(const float2*)&wq_s[oo][ty * 2];
                const float4 b4 = *(const float4*)&wk_s[oo][tx * 4];
                acc[0][0] = fmaf(a.x, b4.x, acc[0][0]);
                acc[0][1] = fmaf(a.x, b4.y, acc[0][1]);
                acc[0][2] = fmaf(a.x, b4.z, acc[0][2]);
                acc[0][3] = fmaf(a.x, b4.w, acc[0][3]);
                acc[1][0] = fmaf(a.y, b4.x, acc[1][0]);
                acc[1][1] = fmaf(a.y, b4.y, acc[1][1]);
                acc[1][2] = fmaf(a.y, b4.z, acc[1][2]);
                acc[1][3] = fmaf(a.y, b4.w, acc[1][3]);
            }
            __syncthreads();
        }

        u16* dh = Bswh + (size_t)T * 8192;
        u16* dl = Bswl + (size_t)T * 8192;
#pragma unroll
        for (int j = 0; j < 2; ++j) {
            const int rimg = nsub * 32 + ty * 2 + j;
            const int base = rimg * 64 + (((tx >> 1) ^ (rimg & 7)) * 8) + (tx & 1) * 4;
            u16x4 hv, lv;
#pragma unroll
            for (int i = 0; i < 4; ++i) {
                hv[i] = bf16_rne(acc[j][i]);
                lv[i] = bf16_rne(acc[j][i] - bf16_tof(hv[i]));
            }
            *(u16x4*)(dh + base) = hv;
            *(u16x4*)(dl + base) = lv;
        }
    } else {
        const int ti    = bx - 72;
        const int kt    = ti & 3;
        const int ntile = (ti >> 2) & 1;
        const int Timg  = 8 + ti;
        const int n0 = ntile * 128, k0 = kt * 64;
        u16* dh = Bswh + (size_t)Timg * 8192;
#pragma unroll
        for (int it = 0; it < 4; ++it) {
            const int s   = it * 256 + t;
            const int row = s >> 3;
            const int ch  = s & 7;
            const int kk  = k0 + (ch ^ (row & 7)) * 8;
            const float4 w0 = *(const float4*)(Wv + (size_t)(n0 + row) * C_DIM + kk);
            const float4 w1 = *(const float4*)(Wv + (size_t)(n0 + row) * C_DIM + kk + 4);
            u16x8 hv;
            hv[0] = bf16_rne(w0.x); hv[1] = bf16_rne(w0.y);
            hv[2] = bf16_rne(w0.z); hv[3] = bf16_rne(w0.w);
            hv[4] = bf16_rne(w1.x); hv[5] = bf16_rne(w1.y);
            hv[6] = bf16_rne(w1.z); hv[7] = bf16_rne(w1.w);
            *(u16x8*)(dh + (size_t)s * 8) = hv;
        }
    }
}

// ---------------------------------------------------------------------------
// xsplit_idx: per 32-pixel strip, all 4 c-chunks:
//  - transpose+split x -> bf16 hi/lo planes
//  - per-pixel f64 GEMV rows (0-7 offsets, 8=u, 9=v), chunk partials kept in
//    registers, summed chunk 0+1+2+3 then +beff (same order as r4-r6 idx path)
//  - finalize idx / kqf / vqf in-kernel (part buffer + idx launch eliminated)
// ---------------------------------------------------------------------------
__global__ __launch_bounds__(256) void xsplit_idx_kernel(
    const float* __restrict__ x, const double* __restrict__ Weffp,
    const double* __restrict__ beff,
    u16* __restrict__ xh, u16* __restrict__ xl,
    int* __restrict__ idx_buf, float* __restrict__ kqf, float* __restrict__ vqf)
{
    __shared__ float  tile[64][33];
    __shared__ double wf[NJ][64];
    __shared__ double osum[NJ][32];

    const int b   = blockIdx.y;
    const int hw0 = blockIdx.x * 32;
    const int t   = threadIdx.x;

    const int p  = t & 31;      // pixel (GEMV role)
    const int g  = t >> 5;      // row group 0..7 (GEMV role)
    const int cl = t & 63;      // c-local (write role)
    const int gg = t >> 6;      // 0..3 (write role)

    double pj[4], pj2[4];

    for (int cy = 0; cy < 4; ++cy) {
        const int c0 = cy * 64;
        if (cy) __syncthreads();   // protect tile/wf overwrite from prior GEMV

        // load x tile [64 c][32 hw]
#pragma unroll
        for (int i = 0; i < 8; ++i) {
            const int s = i * 256 + t;
            const int row = s >> 5;
            const int pp  = s & 31;
            tile[row][pp] = x[((size_t)b * C_DIM + c0 + row) * HW_DIM + hw0 + pp];
        }
        // wf rows: sum of 4 quadrant partials (f64, order 0+1+2+3 as before)
        for (int d = t; d < NJ * 64; d += 256) {
            const int jj = d >> 6, cc = d & 63;
            ((double*)wf)[d] = Weffp[(size_t)(0 * NJ + jj) * C_DIM + c0 + cc]
                             + Weffp[(size_t)(1 * NJ + jj) * C_DIM + c0 + cc]
                             + Weffp[(size_t)(2 * NJ + jj) * C_DIM + c0 + cc]
                             + Weffp[(size_t)(3 * NJ + jj) * C_DIM + c0 + cc];
        }
        __syncthreads();

        // transposed bf16 split-out: thread (cl,gg) -> c = c0+cl, hw rows gg+4i
#pragma unroll
        for (int i = 0; i < 8; ++i) {
            const int hwr = i * 4 + gg;
            const float v = tile[cl][hwr];
            const u16 hbits = bf16_rne(v);
            const float lo = v - bf16_tof(hbits);
            const size_t o = ((size_t)b * HW_DIM + hw0 + hwr) * C_DIM + c0 + cl;
            xh[o] = hbits;
            xl[o] = bf16_rne(lo);
        }

        // GEMV chunk partial: thread (p,g) row j=g; g<2 also row 8+g
        double a0 = 0, a1 = 0;
        for (int c = 0; c < 64; ++c) {
            const double xv = (double)tile[c][p];
            a0 += wf[g][c] * xv;
            if (g < 2) a1 += wf[8 + g][c] * xv;
        }
        pj[cy]  = a0;
        pj2[cy] = a1;
    }

    // chunk sum in order 0,1,2,3 (matches r4-r6 part summation order)
    osum[g][p] = ((pj[0] + pj[1]) + pj[2]) + pj[3];
    if (g < 2) osum[8 + g][p] = ((pj2[0] + pj2[1]) + pj2[2]) + pj2[3];
    __syncthreads();

    if (t < 32) {
        const int hw  = hw0 + t;
        const int pix = b * HW_DIM + hw;
        const int h   = hw >> 6;
        const int w   = hw & 63;
        int r[NREF];
#pragma unroll
        for (int n = 0; n < NREF; ++n) {
            const float ox = (float)(osum[2 * n][t]     + beff[2 * n]);
            const float oy = (float)(osum[2 * n + 1][t] + beff[2 * n + 1]);
            int rx = (int)rintf((float)w + ox);
            int ry = (int)rintf((float)h + oy);
            rx = min(max(rx, 0), W_DIM - 1);
            ry = min(max(ry, 0), H_DIM - 1);
            r[n] = ry * W_DIM + rx;
        }
        int4 outv; outv.x = r[0]; outv.y = r[1]; outv.z = r[2]; outv.w = r[3];
        *(int4*)(idx_buf + (size_t)pix * 4) = outv;
        kqf[pix] = (float)osum[8][t];
        vqf[pix] = (float)(osum[9][t] + beff[8]);
    }
}

// ---------------------------------------------------------------------------
// Merged Kp+V projection: per 32-row m-tile, stage A (xh+xl) ONCE, then
//   Kp = M x (3-pass) and V = Wv x + bv (1-pass, bf16 out) with B restaged
//   from the tiny L2-resident pre-swizzled images.
// Tile 32m x 256n, BK=64, 4 waves (2m x 2n), LDS 72 KB -> 2 blocks/CU.
// ---------------------------------------------------------------------------
__global__ __launch_bounds__(256) void qkv_mfma(
    const u16* __restrict__ xh, const u16* __restrict__ xl,
    const u16* __restrict__ Bswh, const u16* __restrict__ Bswl,
    const float* __restrict__ bv,
    float* __restrict__ Kpt, u16* __restrict__ Vtb)
{
    const int m0 = blockIdx.x * 32;

    __shared__ u16 lds[36864];      // 72 KB
    u16* Ah = lds;                  // [32][64]  4 KB
    u16* Al = lds + 2048;           //           4 KB
    u16* Bh = lds + 4096;           // [256][64] 32 KB
    u16* Bl = lds + 20480;          //           32 KB

    const int t    = threadIdx.x;
    const int lane = t & 63;
    const int wv   = t >> 6;
    const int wm   = (wv >> 1) * 16;    // 0/16
    const int wn   = (wv & 1) * 128;    // 0/128

    f32x4 accK[8] = {};
    f32x4 accV[8] = {};

    for (int kt = 0; kt < 4; ++kt) {
        const int k0 = kt * 64;

        // stage A (hi+lo), inverse-swizzled source
        {
            const int s   = t;
            const int row = s >> 3;
            const int sch = (s & 7) ^ (row & 7);
            const size_t goff = (size_t)(m0 + row) * C_DIM + k0 + sch * 8;
            gload16(xh + goff, (char*)Ah + s * 16);
            gload16(xl + goff, (char*)Al + s * 16);
        }
        // stage B: M images (hi+lo, both ntile halves)
#pragma unroll
        for (int it = 0; it < 8; ++it) {
            const int s  = it * 256 + t;
            const int ni = s >> 10;
            const int sl = s & 1023;
            const size_t Tb = (size_t)(ni * 4 + kt) * 8192;
            gload16(Bswh + Tb + (size_t)sl * 8, (char*)Bh + s * 16);
            gload16(Bswl + Tb + (size_t)sl * 8, (char*)Bl + s * 16);
        }
        __syncthreads();

        // ---- Kp 3-pass ----
#pragma unroll
        for (int ks = 0; ks < 2; ++ks) {
            bf16x8 afh, afl;
            {
                const int row = wm + (lane & 15);
                const int ch  = (ks * 4 + (lane >> 4)) ^ (row & 7);
                const int off = row * 128 + ch * 16;
                afh = *(const bf16x8*)((const char*)Ah + off);
                afl = *(const bf16x8*)((const char*)Al + off);
            }
#pragma unroll
            for (int ng = 0; ng < 2; ++ng)
#pragma unroll
                for (int nt = 0; nt < 4; ++nt) {
                    const int row = wn + ng * 64 + nt * 16 + (lane & 15);
                    const int ch  = (ks * 4 + (lane >> 4)) ^ (row & 7);
                    const int off = row * 128 + ch * 16;
                    const bf16x8 bh = *(const bf16x8*)((const char*)Bh + off);
                    const bf16x8 bl = *(const bf16x8*)((const char*)Bl + off);
                    f32x4 a = accK[ng * 4 + nt];
                    a = __builtin_amdgcn_mfma_f32_16x16x32_bf16(afh, bh, a, 0, 0, 0);
                    a = __builtin_amdgcn_mfma_f32_16x16x32_bf16(afh, bl, a, 0, 0, 0);
                    a = __builtin_amdgcn_mfma_f32_16x16x32_bf16(afl, bh, a, 0, 0, 0);
                    accK[ng * 4 + nt] = a;
                }
        }
        __syncthreads();

        // stage B: V images (hi only) over Bh
#pragma unroll
        for (int it = 0; it < 8; ++it) {
            const int s  = it * 256 + t;
            const int ni = s >> 10;
            const int sl = s & 1023;
            const size_t Tb = (size_t)(8 + ni * 4 + kt) * 8192;
            gload16(Bswh + Tb + (size_t)sl * 8, (char*)Bh + s * 16);
        }
        __syncthreads();

        // ---- V 1-pass ----
#pragma unroll
        for (int ks = 0; ks < 2; ++ks) {
            bf16x8 afh;
            {
                const int row = wm + (lane & 15);
                const int ch  = (ks * 4 + (lane >> 4)) ^ (row & 7);
                const int off = row * 128 + ch * 16;
                afh = *(const bf16x8*)((const char*)Ah + off);
            }
#pragma unroll
            for (int ng = 0; ng < 2; ++ng)
#pragma unroll
                for (int nt = 0; nt < 4; ++nt) {
                    const int row = wn + ng * 64 + nt * 16 + (lane & 15);
                    const int ch  = (ks * 4 + (lane >> 4)) ^ (row & 7);
                    const int off = row * 128 + ch * 16;
                    const bf16x8 bh = *(const bf16x8*)((const char*)Bh + off);
                    accV[ng * 4 + nt] =
                        __builtin_amdgcn_mfma_f32_16x16x32_bf16(afh, bh, accV[ng * 4 + nt], 0, 0, 0);
                }
        }
        __syncthreads();
    }

    // epilogue: C/D layout col=lane&15, row=4*(lane>>4)+reg
    const int col = lane & 15;
    const int rg  = (lane >> 4) * 4;
#pragma unroll
    for (int ng = 0; ng < 2; ++ng)
#pragma unroll
        for (int nt = 0; nt < 4; ++nt) {
            const int n = wn + ng * 64 + nt * 16 + col;
            const float bias = bv[n];
            const int m = m0 + wm + rg;
#pragma unroll
            for (int r = 0; r < 4; ++r) {
                Kpt[(size_t)(m + r) * C_DIM + n] = accK[ng * 4 + nt][r];
                Vtb[(size_t)(m + r) * C_DIM + n] = bf16_rne(accV[ng * 4 + nt][r] + bias);
            }
        }
}

// ---------------------------------------------------------------------------
// attn: logit_n = x_pix . Kp[idx_n] + kq[idx_n] + vq[pix]; softmax; V-sum.
// ---------------------------------------------------------------------------
__global__ __launch_bounds__(1024) void attn_kernel(
    const u16*   __restrict__ xh,
    const u16*   __restrict__ xl,
    const float* __restrict__ Kpt,
    const u16*   __restrict__ Vtb,
    const int*   __restrict__ idx_buf,
    const float* __restrict__ kqf,
    const float* __restrict__ vqf,
    float* __restrict__ out)
{
    __shared__ float trans[16][260];

    const int t    = threadIdx.x;
    const int wave = t >> 6;
    const int lane = t & 63;

    const int pix0 = blockIdx.x * 16;
    const int b    = pix0 / HW_DIM;
    const int hw   = (pix0 % HW_DIM) + wave;
    const int pix  = b * HW_DIM + hw;

    const u16x4 hv = *(const u16x4*)(xh + (size_t)pix * C_DIM + lane * 4);
    const u16x4 lv = *(const u16x4*)(xl + (size_t)pix * C_DIM + lane * 4);
    float q[4];
#pragma unroll
    for (int i = 0; i < 4; ++i) q[i] = bf16_tof(hv[i]) + bf16_tof(lv[i]);

    const int4 iv = *(const int4*)(idx_buf + (size_t)pix * 4);
    int idx[NREF] = {iv.x, iv.y, iv.z, iv.w};
    const float vq = vqf[pix];

    float logit[NREF];
#pragma unroll
    for (int n = 0; n < NREF; ++n) {
        const float* krow = Kpt + ((size_t)b * HW_DIM + idx[n]) * C_DIM;
        float4 kv = *(const float4*)(krow + lane * 4);
        float lp = fmaf(q[3], kv.w, fmaf(q[2], kv.z, fmaf(q[1], kv.y, q[0] * kv.x)));
#pragma unroll
        for (int off = 1; off < 64; off <<= 1) lp += __shfl_xor(lp, off);
        logit[n] = lp + kqf[(size_t)b * HW_DIM + idx[n]] + vq;
    }

    float mx = fmaxf(fmaxf(logit[0], logit[1]), fmaxf(logit[2], logit[3]));
    float e[NREF], s = 0.0f;
#pragma unroll
    for (int n = 0; n < NREF; ++n) { e[n] = expf(logit[n] - mx); s += e[n]; }
    float wgt[NREF];
#pragma unroll
    for (int n = 0; n < NREF; ++n) wgt[n] = e[n] / s;

    float o4[4] = {0.f, 0.f, 0.f, 0.f};
#pragma unroll
    for (int n = 0; n < NREF; ++n) {
        const u16x4 vv = *(const u16x4*)(Vtb + ((size_t)b * HW_DIM + idx[n]) * C_DIM + lane * 4);
        o4[0] = fmaf(wgt[n], bf16_tof(vv[0]), o4[0]);
        o4[1] = fmaf(wgt[n], bf16_tof(vv[1]), o4[1]);
        o4[2] = fmaf(wgt[n], bf16_tof(vv[2]), o4[2]);
        o4[3] = fmaf(wgt[n], bf16_tof(vv[3]), o4[3]);
    }

    *(float4*)&trans[wave][lane * 4] = *(float4*)o4;
    __syncthreads();

    float* ob = out + (size_t)b * C_DIM * HW_DIM + (pix0 % HW_DIM);
    const int px = t & 15;
#pragma unroll
    for (int cc = 0; cc < C_DIM; cc += 64) {
        const int c = cc + (t >> 4);
        ob[(size_t)c * HW_DIM + px] = trans[px][c];
    }
}

// ---------------------------------------------------------------------------
extern "C" void kernel_launch(void* const* d_in, const int* in_sizes, int n_in,
                              void* d_out, int out_size, void* d_ws, size_t ws_size,
                              hipStream_t stream) {
    const float* x    = (const float*)d_in[0];
    const float* Wq   = (const float*)d_in[1];
    const float* bq   = (const float*)d_in[2];
    const float* Wk   = (const float*)d_in[3];
    const float* bk   = (const float*)d_in[4];
    const float* Wv   = (const float*)d_in[5];
    const float* bv   = (const float*)d_in[6];
    const float* Woff = (const float*)d_in[7];
    const float* boff = (const float*)d_in[8];
    float* out = (float*)d_out;

    // Workspace layout (~66 MiB of 256 MiB):
    //   [0,16M)   Kpt f32 (B*HW, C)
    //   [16,24M)  Vtb bf16 (B*HW, C)
    //   [48,56M)  xh bf16
    //   [56,64M)  xl bf16
    //   aux = 64M:
    //     +0      Weffp f64 (4q x NJ x 256) = 80 KB
    //     +128K   beff f64 (9)
    //     +192K   idx int32 (NPIX,4) = 256 KB
    //     +448K   kqf f32 (NPIX) = 64 KB
    //     +512K   vqf f32 (NPIX) = 64 KB
    //     +576K   Bswh u16 (16 tiles x 8192) = 256 KB
    //     +832K   Bswl u16 = 256 KB
    char* ws = (char*)d_ws;
    float*  Kpt   = (float*)ws;
    u16*    Vtb   = (u16*)  (ws + (size_t)16 * 1024 * 1024);
    u16*    xh    = (u16*)  (ws + (size_t)48 * 1024 * 1024);
    u16*    xl    = (u16*)  (ws + (size_t)56 * 1024 * 1024);
    char*   aux   = ws + (size_t)64 * 1024 * 1024;
    double* Weffp = (double*)(aux);
    double* beff  = (double*)(aux + 128 * 1024);
    int*    idxb  = (int*)   (aux + 192 * 1024);
    float*  kqf   = (float*) (aux + 448 * 1024);
    float*  vqf   = (float*) (aux + 512 * 1024);
    u16*    Bswh  = (u16*)   (aux + 576 * 1024);
    u16*    Bswl  = (u16*)   (aux + 832 * 1024);

    // 1) GEMV rows (index path) + M f32 GEMM + W images
    prep_kernel<<<dim3(80), dim3(256), 0, stream>>>(
        Wq, bq, Wk, bk, Wv, Woff, boff, Weffp, beff, Bswh, Bswl);
    // 2) transpose+split x, fused GEMV + idx/kq/vq finalize (part buffer gone)
    xsplit_idx_kernel<<<dim3(HW_DIM / 32, B_DIM), dim3(256), 0, stream>>>(
        x, Weffp, beff, xh, xl, idxb, kqf, vqf);
    // 3) merged Kp (3-pass) + V (1-pass) MFMA, A staged once per m-tile
    qkv_mfma<<<dim3(NPIX / 32), dim3(256), 0, stream>>>(
        xh, xl, Bswh, Bswl, bv, Kpt, Vtb);
    // 4) fused gather-attention
    attn_kernel<<<dim3(NPIX / 16), dim3(1024), 0, stream>>>(
        xh, xl, Kpt, Vtb, idxb, kqf, vqf, out);
}

// Round 14
// 64.992 us; speedup vs baseline: 1.6153x; 1.6153x over previous
//
#include <hip/hip_runtime.h>
#include <math.h>

#define B_DIM   4
#define C_DIM   256
#define H_DIM   64
#define W_DIM   64
#define HW_DIM  4096   // H*W
#define NPIX    (B_DIM * HW_DIM)   // 16384
#define NREF    4
#define NJ      10     // 8 offset rows + u (bq^T Wk) + v (bk^T Wq)

typedef unsigned short u16;
typedef __attribute__((ext_vector_type(4))) unsigned short u16x4;
typedef __attribute__((ext_vector_type(8))) unsigned short u16x8;
typedef __attribute__((ext_vector_type(8))) short bf16x8;
typedef __attribute__((ext_vector_type(4))) float f32x4;

__device__ __forceinline__ u16 bf16_rne(float f) {
    unsigned u = __float_as_uint(f);
    u = u + 0x7FFFu + ((u >> 16) & 1u);
    return (u16)(u >> 16);
}
__device__ __forceinline__ float bf16_tof(u16 h) {
    return __uint_as_float(((unsigned)h) << 16);
}
__device__ __forceinline__ void gload16(const void* g, void* l) {
    __builtin_amdgcn_global_load_lds(
        (const __attribute__((address_space(1))) void*)g,
        (__attribute__((address_space(3))) void*)l, 16, 0, 0);
}

// ---------------------------------------------------------------------------
// prep (80 blocks) — unchanged (proven r6-r13):
//  bx<40 : GEMV-row partials Weffp (f64, INDEX PATH)
//  40<=bx<72 : M = Wq^T Wk sub-tile in f32 -> swizzled bf16 hi/lo image
//  bx>=72 : Wv tiles -> swizzled bf16 hi image (tiles 8..15)
// ---------------------------------------------------------------------------
__global__ __launch_bounds__(256) void prep_kernel(
    const float* __restrict__ Wq, const float* __restrict__ bq,
    const float* __restrict__ Wk, const float* __restrict__ bk,
    const float* __restrict__ Wv,
    const float* __restrict__ Woff, const float* __restrict__ boff,
    double* __restrict__ Weffp, double* __restrict__ beff,
    u16* __restrict__ Bswh, u16* __restrict__ Bswl)
{
    const int bx = blockIdx.x;
    const int t  = threadIdx.x;

    if (bx < 4 * NJ) {
        const int j  = bx >> 2;
        const int q  = bx & 3;
        const int o0 = q * 64;
        const float* Avec = (j < 8) ? (Woff + j * C_DIM) : ((j == 8) ? bq : bk);
        const float* Bmat = (j == 8) ? Wk : Wq;
        double s0 = 0, s1 = 0, s2 = 0, s3 = 0;
        for (int o = o0; o < o0 + 64; o += 4) {
            s0 += (double)Avec[o + 0] * (double)Bmat[(size_t)(o + 0) * C_DIM + t];
            s1 += (double)Avec[o + 1] * (double)Bmat[(size_t)(o + 1) * C_DIM + t];
            s2 += (double)Avec[o + 2] * (double)Bmat[(size_t)(o + 2) * C_DIM + t];
            s3 += (double)Avec[o + 3] * (double)Bmat[(size_t)(o + 3) * C_DIM + t];
        }
        Weffp[(size_t)(q * NJ + j) * C_DIM + t] = (s0 + s1) + (s2 + s3);

        if (q == 0 && j <= 8) {
            __shared__ double red[256];
            red[t] = (j < 8) ? (double)Woff[j * C_DIM + t] * (double)bq[t]
                             : (double)bq[t] * (double)bk[t];
            __syncthreads();
            for (int st = 128; st > 0; st >>= 1) {
                if (t < st) red[t] += red[t + st];
                __syncthreads();
            }
            if (t == 0) beff[j] = (j < 8) ? red[0] + (double)boff[j] : red[0];
        }
    } else if (bx < 72) {
        __shared__ float wq_s[64][32];
        __shared__ float wk_s[64][64];
        const int sub   = bx - 40;
        const int T     = sub >> 2;
        const int nsub  = sub & 3;
        const int ntile = T >> 2;
        const int kt    = T & 3;
        const int nb    = ntile * 128 + nsub * 32;
        const int kb    = kt * 64;

        const int tx = t & 15;
        const int ty = t >> 4;

        float acc[2][4] = {};

        for (int oc = 0; oc < 4; ++oc) {
            const int o0 = oc * 64;
#pragma unroll
            for (int i = 0; i < 2; ++i) {
                const int s = i * 256 + t;
                const int row = s >> 3, c4 = (s & 7) * 4;
                *(float4*)&wq_s[row][c4] =
                    *(const float4*)(Wq + (size_t)(o0 + row) * C_DIM + nb + c4);
            }
#pragma unroll
            for (int i = 0; i < 4; ++i) {
                const int s = i * 256 + t;
                const int row = s >> 4, c4 = (s & 15) * 4;
                *(float4*)&wk_s[row][c4] =
                    *(const float4*)(Wk + (size_t)(o0 + row) * C_DIM + kb + c4);
            }
            __syncthreads();
#pragma unroll 4
            for (int oo = 0; oo < 64; ++oo) {
                const float2 a = *(const float2*)&wq_s[oo][ty * 2];
                const float4 b4 = *(const float4*)&wk_s[oo][tx * 4];
                acc[0][0] = fmaf(a.x, b4.x, acc[0][0]);
                acc[0][1] = fmaf(a.x, b4.y, acc[0][1]);
                acc[0][2] = fmaf(a.x, b4.z, acc[0][2]);
                acc[0][3] = fmaf(a.x, b4.w, acc[0][3]);
                acc[1][0] = fmaf(a.y, b4.x, acc[1][0]);
                acc[1][1] = fmaf(a.y, b4.y, acc[1][1]);
                acc[1][2] = fmaf(a.y, b4.z, acc[1][2]);
                acc[1][3] = fmaf(a.y, b4.w, acc[1][3]);
            }
            __syncthreads();
        }

        u16* dh = Bswh + (size_t)T * 8192;
        u16* dl = Bswl + (size_t)T * 8192;
#pragma unroll
        for (int j = 0; j < 2; ++j) {
            const int rimg = nsub * 32 + ty * 2 + j;
            const int base = rimg * 64 + (((tx >> 1) ^ (rimg & 7)) * 8) + (tx & 1) * 4;
            u16x4 hv, lv;
#pragma unroll
            for (int i = 0; i < 4; ++i) {
                hv[i] = bf16_rne(acc[j][i]);
                lv[i] = bf16_rne(acc[j][i] - bf16_tof(hv[i]));
            }
            *(u16x4*)(dh + base) = hv;
            *(u16x4*)(dl + base) = lv;
        }
    } else {
        const int ti    = bx - 72;
        const int kt    = ti & 3;
        const int ntile = (ti >> 2) & 1;
        const int Timg  = 8 + ti;
        const int n0 = ntile * 128, k0 = kt * 64;
        u16* dh = Bswh + (size_t)Timg * 8192;
#pragma unroll
        for (int it = 0; it < 4; ++it) {
            const int s   = it * 256 + t;
            const int row = s >> 3;
            const int ch  = s & 7;
            const int kk  = k0 + (ch ^ (row & 7)) * 8;
            const float4 w0 = *(const float4*)(Wv + (size_t)(n0 + row) * C_DIM + kk);
            const float4 w1 = *(const float4*)(Wv + (size_t)(n0 + row) * C_DIM + kk + 4);
            u16x8 hv;
            hv[0] = bf16_rne(w0.x); hv[1] = bf16_rne(w0.y);
            hv[2] = bf16_rne(w0.z); hv[3] = bf16_rne(w0.w);
            hv[4] = bf16_rne(w1.x); hv[5] = bf16_rne(w1.y);
            hv[6] = bf16_rne(w1.z); hv[7] = bf16_rne(w1.w);
            *(u16x8*)(dh + (size_t)s * 8) = hv;
        }
    }
}

// ---------------------------------------------------------------------------
// xsplit (r11 version, proven): transpose+split x to bf16 planes AND per-pixel
// f64 GEMV chunk partials to the part buffer. 1024 blocks.
// ---------------------------------------------------------------------------
__global__ __launch_bounds__(256) void xsplit_kernel(
    const float* __restrict__ x, const double* __restrict__ Weffp,
    u16* __restrict__ xh, u16* __restrict__ xl, double* __restrict__ part)
{
    __shared__ float  tile[64][65];
    __shared__ double wf[NJ][64];
    const int b   = blockIdx.z;
    const int cy  = blockIdx.y;
    const int c0  = cy * 64;
    const int hw0 = blockIdx.x * 64;
    const int t   = threadIdx.x;
    const int r4  = t >> 6;
    const int col = t & 63;

#pragma unroll
    for (int i = 0; i < 16; ++i) {
        const int row = i * 4 + r4;
        tile[row][col] = x[((size_t)b * C_DIM + c0 + row) * HW_DIM + hw0 + col];
    }
    for (int d = t; d < NJ * 64; d += 256) {
        const int jj = d >> 6, cc = d & 63;
        ((double*)wf)[d] = Weffp[(size_t)(0 * NJ + jj) * C_DIM + c0 + cc]
                         + Weffp[(size_t)(1 * NJ + jj) * C_DIM + c0 + cc]
                         + Weffp[(size_t)(2 * NJ + jj) * C_DIM + c0 + cc]
                         + Weffp[(size_t)(3 * NJ + jj) * C_DIM + c0 + cc];
    }
    __syncthreads();

#pragma unroll
    for (int i = 0; i < 16; ++i) {
        const int hwr = i * 4 + r4;
        const float v = tile[col][hwr];
        const u16 h = bf16_rne(v);
        const float lo = v - bf16_tof(h);
        const size_t o = ((size_t)b * HW_DIM + hw0 + hwr) * C_DIM + c0 + col;
        xh[o] = h;
        xl[o] = bf16_rne(lo);
    }

    const int p = col, g = r4;
    double a0 = 0, a1 = 0, a2 = 0;
    for (int c = 0; c < 64; ++c) {
        const double xv = (double)tile[c][p];
        a0 += wf[2 * g][c] * xv;
        a1 += wf[2 * g + 1][c] * xv;
        if (g < 2) a2 += wf[8 + g][c] * xv;
    }
    const int pix = b * HW_DIM + hw0 + p;
    part[(size_t)(cy * NJ + 2 * g) * NPIX + pix]     = a0;
    part[(size_t)(cy * NJ + 2 * g + 1) * NPIX + pix] = a1;
    if (g < 2) part[(size_t)(cy * NJ + 8 + g) * NPIX + pix] = a2;
}

// ---------------------------------------------------------------------------
// idx finalize (r11 version — INDEX PATH identical numerics) + kq/vq.
// ---------------------------------------------------------------------------
__global__ __launch_bounds__(256) void idx_kernel(
    const double* __restrict__ part, const double* __restrict__ beff,
    int* __restrict__ idx_buf, float* __restrict__ kqf, float* __restrict__ vqf)
{
    const int pix = blockIdx.x * 256 + threadIdx.x;
    const int hw  = pix & (HW_DIM - 1);
    const int h   = hw >> 6;
    const int w   = hw & 63;

    double o[8];
#pragma unroll
    for (int j = 0; j < 8; ++j)
        o[j] = part[(size_t)(0 * NJ + j) * NPIX + pix] + part[(size_t)(1 * NJ + j) * NPIX + pix]
             + part[(size_t)(2 * NJ + j) * NPIX + pix] + part[(size_t)(3 * NJ + j) * NPIX + pix]
             + beff[j];

    int r[NREF];
#pragma unroll
    for (int n = 0; n < NREF; ++n) {
        const float ox = (float)o[2 * n];
        const float oy = (float)o[2 * n + 1];
        int rx = (int)rintf((float)w + ox);
        int ry = (int)rintf((float)h + oy);
        rx = min(max(rx, 0), W_DIM - 1);
        ry = min(max(ry, 0), H_DIM - 1);
        r[n] = ry * W_DIM + rx;
    }
    int4 outv; outv.x = r[0]; outv.y = r[1]; outv.z = r[2]; outv.w = r[3];
    *(int4*)(idx_buf + (size_t)pix * 4) = outv;

    const double kq = part[(size_t)(0 * NJ + 8) * NPIX + pix] + part[(size_t)(1 * NJ + 8) * NPIX + pix]
                    + part[(size_t)(2 * NJ + 8) * NPIX + pix] + part[(size_t)(3 * NJ + 8) * NPIX + pix];
    const double vq = part[(size_t)(0 * NJ + 9) * NPIX + pix] + part[(size_t)(1 * NJ + 9) * NPIX + pix]
                    + part[(size_t)(2 * NJ + 9) * NPIX + pix] + part[(size_t)(3 * NJ + 9) * NPIX + pix]
                    + beff[8];
    kqf[pix] = (float)kq;
    vqf[pix] = (float)vq;
}

// ---------------------------------------------------------------------------
// Merged Kp+V projection: per 32-row m-tile, stage A once; Kp = M x (3-pass)
// -> f32 out (bf16 FAILED r13: |Kp|~O(10), bf16 quant -> logit noise ~0.5);
// V = Wv x + bv (1-pass) -> bf16 out (proven r12).
// Tile 32m x 256n, BK=64, 4 waves, LDS 72 KB -> 2 blocks/CU, 512 blocks.
// ---------------------------------------------------------------------------
__global__ __launch_bounds__(256) void qkv_mfma(
    const u16* __restrict__ xh, const u16* __restrict__ xl,
    const u16* __restrict__ Bswh, const u16* __restrict__ Bswl,
    const float* __restrict__ bv,
    float* __restrict__ Kpt, u16* __restrict__ Vtb)
{
    const int m0 = blockIdx.x * 32;

    __shared__ u16 lds[36864];      // 72 KB
    u16* Ah = lds;                  // [32][64]  4 KB
    u16* Al = lds + 2048;           //           4 KB
    u16* Bh = lds + 4096;           // [256][64] 32 KB
    u16* Bl = lds + 20480;          //           32 KB

    const int t    = threadIdx.x;
    const int lane = t & 63;
    const int wv   = t >> 6;
    const int wm   = (wv >> 1) * 16;    // 0/16
    const int wn   = (wv & 1) * 128;    // 0/128

    f32x4 accK[8] = {};
    f32x4 accV[8] = {};

    for (int kt = 0; kt < 4; ++kt) {
        const int k0 = kt * 64;

        // stage A (hi+lo), inverse-swizzled source
        {
            const int s   = t;
            const int row = s >> 3;
            const int sch = (s & 7) ^ (row & 7);
            const size_t goff = (size_t)(m0 + row) * C_DIM + k0 + sch * 8;
            gload16(xh + goff, (char*)Ah + s * 16);
            gload16(xl + goff, (char*)Al + s * 16);
        }
        // stage B: M images (hi+lo, both ntile halves)
#pragma unroll
        for (int it = 0; it < 8; ++it) {
            const int s  = it * 256 + t;
            const int ni = s >> 10;
            const int sl = s & 1023;
            const size_t Tb = (size_t)(ni * 4 + kt) * 8192;
            gload16(Bswh + Tb + (size_t)sl * 8, (char*)Bh + s * 16);
            gload16(Bswl + Tb + (size_t)sl * 8, (char*)Bl + s * 16);
        }
        __syncthreads();

        // ---- Kp 3-pass ----
#pragma unroll
        for (int ks = 0; ks < 2; ++ks) {
            bf16x8 afh, afl;
            {
                const int row = wm + (lane & 15);
                const int ch  = (ks * 4 + (lane >> 4)) ^ (row & 7);
                const int off = row * 128 + ch * 16;
                afh = *(const bf16x8*)((const char*)Ah + off);
                afl = *(const bf16x8*)((const char*)Al + off);
            }
#pragma unroll
            for (int ng = 0; ng < 2; ++ng)
#pragma unroll
                for (int nt = 0; nt < 4; ++nt) {
                    const int row = wn + ng * 64 + nt * 16 + (lane & 15);
                    const int ch  = (ks * 4 + (lane >> 4)) ^ (row & 7);
                    const int off = row * 128 + ch * 16;
                    const bf16x8 bh = *(const bf16x8*)((const char*)Bh + off);
                    const bf16x8 bl = *(const bf16x8*)((const char*)Bl + off);
                    f32x4 a = accK[ng * 4 + nt];
                    a = __builtin_amdgcn_mfma_f32_16x16x32_bf16(afh, bh, a, 0, 0, 0);
                    a = __builtin_amdgcn_mfma_f32_16x16x32_bf16(afh, bl, a, 0, 0, 0);
                    a = __builtin_amdgcn_mfma_f32_16x16x32_bf16(afl, bh, a, 0, 0, 0);
                    accK[ng * 4 + nt] = a;
                }
        }
        __syncthreads();

        // stage B: V images (hi only) over Bh
#pragma unroll
        for (int it = 0; it < 8; ++it) {
            const int s  = it * 256 + t;
            const int ni = s >> 10;
            const int sl = s & 1023;
            const size_t Tb = (size_t)(8 + ni * 4 + kt) * 8192;
            gload16(Bswh + Tb + (size_t)sl * 8, (char*)Bh + s * 16);
        }
        __syncthreads();

        // ---- V 1-pass ----
#pragma unroll
        for (int ks = 0; ks < 2; ++ks) {
            bf16x8 afh;
            {
                const int row = wm + (lane & 15);
                const int ch  = (ks * 4 + (lane >> 4)) ^ (row & 7);
                const int off = row * 128 + ch * 16;
                afh = *(const bf16x8*)((const char*)Ah + off);
            }
#pragma unroll
            for (int ng = 0; ng < 2; ++ng)
#pragma unroll
                for (int nt = 0; nt < 4; ++nt) {
                    const int row = wn + ng * 64 + nt * 16 + (lane & 15);
                    const int ch  = (ks * 4 + (lane >> 4)) ^ (row & 7);
                    const int off = row * 128 + ch * 16;
                    const bf16x8 bh = *(const bf16x8*)((const char*)Bh + off);
                    accV[ng * 4 + nt] =
                        __builtin_amdgcn_mfma_f32_16x16x32_bf16(afh, bh, accV[ng * 4 + nt], 0, 0, 0);
                }
        }
        __syncthreads();
    }

    // epilogue: C/D layout col=lane&15, row=4*(lane>>4)+reg
    const int col = lane & 15;
    const int rg  = (lane >> 4) * 4;
#pragma unroll
    for (int ng = 0; ng < 2; ++ng)
#pragma unroll
        for (int nt = 0; nt < 4; ++nt) {
            const int n = wn + ng * 64 + nt * 16 + col;
            const float bias = bv[n];
            const int m = m0 + wm + rg;
#pragma unroll
            for (int r = 0; r < 4; ++r) {
                Kpt[(size_t)(m + r) * C_DIM + n] = accK[ng * 4 + nt][r];
                Vtb[(size_t)(m + r) * C_DIM + n] = bf16_rne(accV[ng * 4 + nt][r] + bias);
            }
        }
}

// ---------------------------------------------------------------------------
// attn: logit_n = x_pix . Kp[idx_n] + kq[idx_n] + vq[pix]; softmax; V-sum.
// Kp gathered f32; V gathered bf16. One wave per pixel.
// ---------------------------------------------------------------------------
__global__ __launch_bounds__(1024) void attn_kernel(
    const u16*   __restrict__ xh,
    const u16*   __restrict__ xl,
    const float* __restrict__ Kpt,
    const u16*   __restrict__ Vtb,
    const int*   __restrict__ idx_buf,
    const float* __restrict__ kqf,
    const float* __restrict__ vqf,
    float* __restrict__ out)
{
    __shared__ float trans[16][260];

    const int t    = threadIdx.x;
    const int wave = t >> 6;
    const int lane = t & 63;

    const int pix0 = blockIdx.x * 16;
    const int b    = pix0 / HW_DIM;
    const int hw   = (pix0 % HW_DIM) + wave;
    const int pix  = b * HW_DIM + hw;

    const u16x4 hv = *(const u16x4*)(xh + (size_t)pix * C_DIM + lane * 4);
    const u16x4 lv = *(const u16x4*)(xl + (size_t)pix * C_DIM + lane * 4);
    float q[4];
#pragma unroll
    for (int i = 0; i < 4; ++i) q[i] = bf16_tof(hv[i]) + bf16_tof(lv[i]);

    const int4 iv = *(const int4*)(idx_buf + (size_t)pix * 4);
    int idx[NREF] = {iv.x, iv.y, iv.z, iv.w};
    const float vq = vqf[pix];

    float logit[NREF];
#pragma unroll
    for (int n = 0; n < NREF; ++n) {
        const float* krow = Kpt + ((size_t)b * HW_DIM + idx[n]) * C_DIM;
        float4 kv = *(const float4*)(krow + lane * 4);
        float lp = fmaf(q[3], kv.w, fmaf(q[2], kv.z, fmaf(q[1], kv.y, q[0] * kv.x)));
#pragma unroll
        for (int off = 1; off < 64; off <<= 1) lp += __shfl_xor(lp, off);
        logit[n] = lp + kqf[(size_t)b * HW_DIM + idx[n]] + vq;
    }

    float mx = fmaxf(fmaxf(logit[0], logit[1]), fmaxf(logit[2], logit[3]));
    float e[NREF], s = 0.0f;
#pragma unroll
    for (int n = 0; n < NREF; ++n) { e[n] = expf(logit[n] - mx); s += e[n]; }
    float wgt[NREF];
#pragma unroll
    for (int n = 0; n < NREF; ++n) wgt[n] = e[n] / s;

    float o4[4] = {0.f, 0.f, 0.f, 0.f};
#pragma unroll
    for (int n = 0; n < NREF; ++n) {
        const u16x4 vv = *(const u16x4*)(Vtb + ((size_t)b * HW_DIM + idx[n]) * C_DIM + lane * 4);
        o4[0] = fmaf(wgt[n], bf16_tof(vv[0]), o4[0]);
        o4[1] = fmaf(wgt[n], bf16_tof(vv[1]), o4[1]);
        o4[2] = fmaf(wgt[n], bf16_tof(vv[2]), o4[2]);
        o4[3] = fmaf(wgt[n], bf16_tof(vv[3]), o4[3]);
    }

    *(float4*)&trans[wave][lane * 4] = *(float4*)o4;
    __syncthreads();

    float* ob = out + (size_t)b * C_DIM * HW_DIM + (pix0 % HW_DIM);
    const int px = t & 15;
#pragma unroll
    for (int cc = 0; cc < C_DIM; cc += 64) {
        const int c = cc + (t >> 4);
        ob[(size_t)c * HW_DIM + px] = trans[px][c];
    }
}

// ---------------------------------------------------------------------------
extern "C" void kernel_launch(void* const* d_in, const int* in_sizes, int n_in,
                              void* d_out, int out_size, void* d_ws, size_t ws_size,
                              hipStream_t stream) {
    const float* x    = (const float*)d_in[0];
    const float* Wq   = (const float*)d_in[1];
    const float* bq   = (const float*)d_in[2];
    const float* Wk   = (const float*)d_in[3];
    const float* bk   = (const float*)d_in[4];
    const float* Wv   = (const float*)d_in[5];
    const float* bv   = (const float*)d_in[6];
    const float* Woff = (const float*)d_in[7];
    const float* boff = (const float*)d_in[8];
    float* out = (float*)d_out;

    // Workspace layout (~72 MiB of 256 MiB):
    //   [0,16M)   Kpt f32 (B*HW, C)
    //   [16,24M)  Vtb bf16
    //   [48,56M)  xh bf16
    //   [56,64M)  xl bf16
    //   aux = 64M:
    //     +0      Weffp f64 (4q x NJ x 256) = 80 KB
    //     +128K   beff f64 (9)
    //     +192K   idx int32 (NPIX,4) = 256 KB
    //     +448K   kqf f32 (NPIX) = 64 KB
    //     +512K   vqf f32 (NPIX) = 64 KB
    //     +576K   Bswh u16 (16 tiles x 8192) = 256 KB
    //     +832K   Bswl u16 = 256 KB
    //     +2M     part f64 (4q x NJ x NPIX) = 5.25 MB
    char* ws = (char*)d_ws;
    float*  Kpt   = (float*)ws;
    u16*    Vtb   = (u16*)  (ws + (size_t)16 * 1024 * 1024);
    u16*    xh    = (u16*)  (ws + (size_t)48 * 1024 * 1024);
    u16*    xl    = (u16*)  (ws + (size_t)56 * 1024 * 1024);
    char*   aux   = ws + (size_t)64 * 1024 * 1024;
    double* Weffp = (double*)(aux);
    double* beff  = (double*)(aux + 128 * 1024);
    int*    idxb  = (int*)   (aux + 192 * 1024);
    float*  kqf   = (float*) (aux + 448 * 1024);
    float*  vqf   = (float*) (aux + 512 * 1024);
    u16*    Bswh  = (u16*)   (aux + 576 * 1024);
    u16*    Bswl  = (u16*)   (aux + 832 * 1024);
    double* part  = (double*)(aux + 2 * 1024 * 1024);

    // 1) GEMV rows (index path) + M f32 GEMM + W images
    prep_kernel<<<dim3(80), dim3(256), 0, stream>>>(
        Wq, bq, Wk, bk, Wv, Woff, boff, Weffp, beff, Bswh, Bswl);
    // 2) transpose+split x, fused per-pixel GEMV partials (r11 version)
    xsplit_kernel<<<dim3(HW_DIM / 64, C_DIM / 64, B_DIM), dim3(256), 0, stream>>>(
        x, Weffp, xh, xl, part);
    // 3) finalize indices + kq/vq scalars (r11 version)
    idx_kernel<<<dim3(NPIX / 256), dim3(256), 0, stream>>>(part, beff, idxb, kqf, vqf);
    // 4) merged Kp (3-pass, f32 out) + V (1-pass, bf16 out) MFMA
    qkv_mfma<<<dim3(NPIX / 32), dim3(256), 0, stream>>>(
        xh, xl, Bswh, Bswl, bv, Kpt, Vtb);
    // 5) fused gather-attention
    attn_kernel<<<dim3(NPIX / 16), dim3(1024), 0, stream>>>(
        xh, xl, Kpt, Vtb, idxb, kqf, vqf, out);
}

// Round 15
// 59.287 us; speedup vs baseline: 1.7708x; 1.0962x over previous
//
#include <hip/hip_runtime.h>
#include <math.h>

#define B_DIM   4
#define C_DIM   256
#define H_DIM   64
#define W_DIM   64
#define HW_DIM  4096   // H*W
#define NPIX    (B_DIM * HW_DIM)   // 16384
#define NREF    4
#define NJW     9      // Weffp rows: 8 offset rows + u (bq^T Wk)
#define NPJ     8      // per-pixel GEMV rows (offsets only)

typedef unsigned short u16;
typedef __attribute__((ext_vector_type(4))) unsigned short u16x4;
typedef __attribute__((ext_vector_type(8))) unsigned short u16x8;
typedef __attribute__((ext_vector_type(8))) short bf16x8;
typedef __attribute__((ext_vector_type(4))) float f32x4;

__device__ __forceinline__ u16 bf16_rne(float f) {
    unsigned u = __float_as_uint(f);
    u = u + 0x7FFFu + ((u >> 16) & 1u);
    return (u16)(u >> 16);
}
__device__ __forceinline__ float bf16_tof(u16 h) {
    return __uint_as_float(((unsigned)h) << 16);
}
__device__ __forceinline__ void gload16(const void* g, void* l) {
    __builtin_amdgcn_global_load_lds(
        (const __attribute__((address_space(1))) void*)g,
        (__attribute__((address_space(3))) void*)l, 16, 0, 0);
}

// ---------------------------------------------------------------------------
// prep (76 blocks):
//  bx<36 : GEMV-row partials Weffp (f64): j<8 offsets (INDEX PATH, bit-identical
//          accumulation to r4-r14), j=8: u = bq^T Wk. q==0 & j<8 also beff[j].
//  36<=bx<68 : Mt = Wk^T Wq sub-tile [32 n][64 k] f32 (so Yp = Mt x = M^T x),
//          written as swizzled bf16 hi/lo staging image (tiles 0-7).
//  bx>=68 : Wv tiles -> swizzled bf16 hi image (tiles 8-15).
// ---------------------------------------------------------------------------
__global__ __launch_bounds__(256) void prep_kernel(
    const float* __restrict__ Wq, const float* __restrict__ bq,
    const float* __restrict__ Wk, const float* __restrict__ bk,
    const float* __restrict__ Wv,
    const float* __restrict__ Woff, const float* __restrict__ boff,
    double* __restrict__ Weffp, double* __restrict__ beff,
    u16* __restrict__ Bswh, u16* __restrict__ Bswl)
{
    const int bx = blockIdx.x;
    const int t  = threadIdx.x;
    (void)bk;

    if (bx < 4 * NJW) {
        const int j  = bx >> 2;
        const int q  = bx & 3;
        const int o0 = q * 64;
        const float* Avec = (j < 8) ? (Woff + j * C_DIM) : bq;
        const float* Bmat = (j == 8) ? Wk : Wq;
        double s0 = 0, s1 = 0, s2 = 0, s3 = 0;
        for (int o = o0; o < o0 + 64; o += 4) {
            s0 += (double)Avec[o + 0] * (double)Bmat[(size_t)(o + 0) * C_DIM + t];
            s1 += (double)Avec[o + 1] * (double)Bmat[(size_t)(o + 1) * C_DIM + t];
            s2 += (double)Avec[o + 2] * (double)Bmat[(size_t)(o + 2) * C_DIM + t];
            s3 += (double)Avec[o + 3] * (double)Bmat[(size_t)(o + 3) * C_DIM + t];
        }
        Weffp[(size_t)(q * NJW + j) * C_DIM + t] = (s0 + s1) + (s2 + s3);

        if (q == 0 && j < 8) {
            __shared__ double red[256];
            red[t] = (double)Woff[j * C_DIM + t] * (double)bq[t];
            __syncthreads();
            for (int st = 128; st > 0; st >>= 1) {
                if (t < st) red[t] += red[t + st];
                __syncthreads();
            }
            if (t == 0) beff[j] = red[0] + (double)boff[j];
        }
    } else if (bx < 68) {
        // ---- Mt sub-tile: Mt[n][k] = sum_o Wk[o][n] * Wq[o][k] ----
        __shared__ float wn_s[64][32];   // n-side (from Wk)
        __shared__ float wk_s[64][64];   // k-side (from Wq)
        const int sub   = bx - 36;
        const int T     = sub >> 2;          // ntile*4 + kt
        const int nsub  = sub & 3;
        const int ntile = T >> 2;
        const int kt    = T & 3;
        const int nb    = ntile * 128 + nsub * 32;
        const int kb    = kt * 64;

        const int tx = t & 15;
        const int ty = t >> 4;

        float acc[2][4] = {};

        for (int oc = 0; oc < 4; ++oc) {
            const int o0 = oc * 64;
#pragma unroll
            for (int i = 0; i < 2; ++i) {
                const int s = i * 256 + t;
                const int row = s >> 3, c4 = (s & 7) * 4;
                *(float4*)&wn_s[row][c4] =
                    *(const float4*)(Wk + (size_t)(o0 + row) * C_DIM + nb + c4);
            }
#pragma unroll
            for (int i = 0; i < 4; ++i) {
                const int s = i * 256 + t;
                const int row = s >> 4, c4 = (s & 15) * 4;
                *(float4*)&wk_s[row][c4] =
                    *(const float4*)(Wq + (size_t)(o0 + row) * C_DIM + kb + c4);
            }
            __syncthreads();
#pragma unroll 4
            for (int oo = 0; oo < 64; ++oo) {
                const float2 a = *(const float2*)&wn_s[oo][ty * 2];
                const float4 b4 = *(const float4*)&wk_s[oo][tx * 4];
                acc[0][0] = fmaf(a.x, b4.x, acc[0][0]);
                acc[0][1] = fmaf(a.x, b4.y, acc[0][1]);
                acc[0][2] = fmaf(a.x, b4.z, acc[0][2]);
                acc[0][3] = fmaf(a.x, b4.w, acc[0][3]);
                acc[1][0] = fmaf(a.y, b4.x, acc[1][0]);
                acc[1][1] = fmaf(a.y, b4.y, acc[1][1]);
                acc[1][2] = fmaf(a.y, b4.z, acc[1][2]);
                acc[1][3] = fmaf(a.y, b4.w, acc[1][3]);
            }
            __syncthreads();
        }

        u16* dh = Bswh + (size_t)T * 8192;
        u16* dl = Bswl + (size_t)T * 8192;
#pragma unroll
        for (int j = 0; j < 2; ++j) {
            const int rimg = nsub * 32 + ty * 2 + j;
            const int base = rimg * 64 + (((tx >> 1) ^ (rimg & 7)) * 8) + (tx & 1) * 4;
            u16x4 hv, lv;
#pragma unroll
            for (int i = 0; i < 4; ++i) {
                hv[i] = bf16_rne(acc[j][i]);
                lv[i] = bf16_rne(acc[j][i] - bf16_tof(hv[i]));
            }
            *(u16x4*)(dh + base) = hv;
            *(u16x4*)(dl + base) = lv;
        }
    } else {
        const int ti    = bx - 68;
        const int kt    = ti & 3;
        const int ntile = (ti >> 2) & 1;
        const int Timg  = 8 + ti;
        const int n0 = ntile * 128, k0 = kt * 64;
        u16* dh = Bswh + (size_t)Timg * 8192;
#pragma unroll
        for (int it = 0; it < 4; ++it) {
            const int s   = it * 256 + t;
            const int row = s >> 3;
            const int ch  = s & 7;
            const int kk  = k0 + (ch ^ (row & 7)) * 8;
            const float4 w0 = *(const float4*)(Wv + (size_t)(n0 + row) * C_DIM + kk);
            const float4 w1 = *(const float4*)(Wv + (size_t)(n0 + row) * C_DIM + kk + 4);
            u16x8 hv;
            hv[0] = bf16_rne(w0.x); hv[1] = bf16_rne(w0.y);
            hv[2] = bf16_rne(w0.z); hv[3] = bf16_rne(w0.w);
            hv[4] = bf16_rne(w1.x); hv[5] = bf16_rne(w1.y);
            hv[6] = bf16_rne(w1.z); hv[7] = bf16_rne(w1.w);
            *(u16x8*)(dh + (size_t)s * 8) = hv;
        }
    }
}

// ---------------------------------------------------------------------------
// xsplit (r11 structure, proven): transpose+split x to bf16 planes AND
// per-pixel f64 GEMV chunk partials (rows 0-7 only). Block (0,0,0) also
// finalizes the u bias vector (f32) from Weffp row 8.
// ---------------------------------------------------------------------------
__global__ __launch_bounds__(256) void xsplit_kernel(
    const float* __restrict__ x, const double* __restrict__ Weffp,
    u16* __restrict__ xh, u16* __restrict__ xl, double* __restrict__ part,
    float* __restrict__ uf)
{
    __shared__ float  tile[64][65];
    __shared__ double wf[NPJ][64];
    const int b   = blockIdx.z;
    const int cy  = blockIdx.y;
    const int c0  = cy * 64;
    const int hw0 = blockIdx.x * 64;
    const int t   = threadIdx.x;
    const int r4  = t >> 6;
    const int col = t & 63;

    if (blockIdx.x == 0 && blockIdx.y == 0 && blockIdx.z == 0) {
        const double uu = Weffp[(size_t)(0 * NJW + 8) * C_DIM + t]
                        + Weffp[(size_t)(1 * NJW + 8) * C_DIM + t]
                        + Weffp[(size_t)(2 * NJW + 8) * C_DIM + t]
                        + Weffp[(size_t)(3 * NJW + 8) * C_DIM + t];
        uf[t] = (float)uu;
    }

#pragma unroll
    for (int i = 0; i < 16; ++i) {
        const int row = i * 4 + r4;
        tile[row][col] = x[((size_t)b * C_DIM + c0 + row) * HW_DIM + hw0 + col];
    }
    for (int d = t; d < NPJ * 64; d += 256) {
        const int jj = d >> 6, cc = d & 63;
        ((double*)wf)[d] = Weffp[(size_t)(0 * NJW + jj) * C_DIM + c0 + cc]
                         + Weffp[(size_t)(1 * NJW + jj) * C_DIM + c0 + cc]
                         + Weffp[(size_t)(2 * NJW + jj) * C_DIM + c0 + cc]
                         + Weffp[(size_t)(3 * NJW + jj) * C_DIM + c0 + cc];
    }
    __syncthreads();

#pragma unroll
    for (int i = 0; i < 16; ++i) {
        const int hwr = i * 4 + r4;
        const float v = tile[col][hwr];
        const u16 h = bf16_rne(v);
        const float lo = v - bf16_tof(h);
        const size_t o = ((size_t)b * HW_DIM + hw0 + hwr) * C_DIM + c0 + col;
        xh[o] = h;
        xl[o] = bf16_rne(lo);
    }

    const int p = col, g = r4;
    double a0 = 0, a1 = 0;
    for (int c = 0; c < 64; ++c) {
        const double xv = (double)tile[c][p];
        a0 += wf[2 * g][c] * xv;
        a1 += wf[2 * g + 1][c] * xv;
    }
    const int pix = b * HW_DIM + hw0 + p;
    part[(size_t)(cy * NPJ + 2 * g) * NPIX + pix]     = a0;
    part[(size_t)(cy * NPJ + 2 * g + 1) * NPIX + pix] = a1;
}

// ---------------------------------------------------------------------------
// Merged Yp+V projection: per 32-row m-tile, stage A once;
//   Yp = Mt x + u  (3-pass, f32 out)  [Mt = M^T so logit = Yp_pix . x_gather]
//   V  = Wv x + bv (1-pass, bf16 out)
// Tile 32m x 256n, BK=64, 4 waves, LDS 72 KB -> 2 blocks/CU, 512 blocks.
// ---------------------------------------------------------------------------
__global__ __launch_bounds__(256) void qkv_mfma(
    const u16* __restrict__ xh, const u16* __restrict__ xl,
    const u16* __restrict__ Bswh, const u16* __restrict__ Bswl,
    const float* __restrict__ uf, const float* __restrict__ bv,
    float* __restrict__ Ypt, u16* __restrict__ Vtb)
{
    const int m0 = blockIdx.x * 32;

    __shared__ u16 lds[36864];      // 72 KB
    u16* Ah = lds;                  // [32][64]  4 KB
    u16* Al = lds + 2048;           //           4 KB
    u16* Bh = lds + 4096;           // [256][64] 32 KB
    u16* Bl = lds + 20480;          //           32 KB

    const int t    = threadIdx.x;
    const int lane = t & 63;
    const int wv   = t >> 6;
    const int wm   = (wv >> 1) * 16;    // 0/16
    const int wn   = (wv & 1) * 128;    // 0/128

    f32x4 accK[8] = {};
    f32x4 accV[8] = {};

    for (int kt = 0; kt < 4; ++kt) {
        const int k0 = kt * 64;

        // stage A (hi+lo), inverse-swizzled source
        {
            const int s   = t;
            const int row = s >> 3;
            const int sch = (s & 7) ^ (row & 7);
            const size_t goff = (size_t)(m0 + row) * C_DIM + k0 + sch * 8;
            gload16(xh + goff, (char*)Ah + s * 16);
            gload16(xl + goff, (char*)Al + s * 16);
        }
        // stage B: Mt images (hi+lo, both ntile halves)
#pragma unroll
        for (int it = 0; it < 8; ++it) {
            const int s  = it * 256 + t;
            const int ni = s >> 10;
            const int sl = s & 1023;
            const size_t Tb = (size_t)(ni * 4 + kt) * 8192;
            gload16(Bswh + Tb + (size_t)sl * 8, (char*)Bh + s * 16);
            gload16(Bswl + Tb + (size_t)sl * 8, (char*)Bl + s * 16);
        }
        __syncthreads();

        // ---- Yp 3-pass ----
#pragma unroll
        for (int ks = 0; ks < 2; ++ks) {
            bf16x8 afh, afl;
            {
                const int row = wm + (lane & 15);
                const int ch  = (ks * 4 + (lane >> 4)) ^ (row & 7);
                const int off = row * 128 + ch * 16;
                afh = *(const bf16x8*)((const char*)Ah + off);
                afl = *(const bf16x8*)((const char*)Al + off);
            }
#pragma unroll
            for (int ng = 0; ng < 2; ++ng)
#pragma unroll
                for (int nt = 0; nt < 4; ++nt) {
                    const int row = wn + ng * 64 + nt * 16 + (lane & 15);
                    const int ch  = (ks * 4 + (lane >> 4)) ^ (row & 7);
                    const int off = row * 128 + ch * 16;
                    const bf16x8 bh = *(const bf16x8*)((const char*)Bh + off);
                    const bf16x8 bl = *(const bf16x8*)((const char*)Bl + off);
                    f32x4 a = accK[ng * 4 + nt];
                    a = __builtin_amdgcn_mfma_f32_16x16x32_bf16(afh, bh, a, 0, 0, 0);
                    a = __builtin_amdgcn_mfma_f32_16x16x32_bf16(afh, bl, a, 0, 0, 0);
                    a = __builtin_amdgcn_mfma_f32_16x16x32_bf16(afl, bh, a, 0, 0, 0);
                    accK[ng * 4 + nt] = a;
                }
        }
        __syncthreads();

        // stage B: V images (hi only) over Bh
#pragma unroll
        for (int it = 0; it < 8; ++it) {
            const int s  = it * 256 + t;
            const int ni = s >> 10;
            const int sl = s & 1023;
            const size_t Tb = (size_t)(8 + ni * 4 + kt) * 8192;
            gload16(Bswh + Tb + (size_t)sl * 8, (char*)Bh + s * 16);
        }
        __syncthreads();

        // ---- V 1-pass ----
#pragma unroll
        for (int ks = 0; ks < 2; ++ks) {
            bf16x8 afh;
            {
                const int row = wm + (lane & 15);
                const int ch  = (ks * 4 + (lane >> 4)) ^ (row & 7);
                const int off = row * 128 + ch * 16;
                afh = *(const bf16x8*)((const char*)Ah + off);
            }
#pragma unroll
            for (int ng = 0; ng < 2; ++ng)
#pragma unroll
                for (int nt = 0; nt < 4; ++nt) {
                    const int row = wn + ng * 64 + nt * 16 + (lane & 15);
                    const int ch  = (ks * 4 + (lane >> 4)) ^ (row & 7);
                    const int off = row * 128 + ch * 16;
                    const bf16x8 bh = *(const bf16x8*)((const char*)Bh + off);
                    accV[ng * 4 + nt] =
                        __builtin_amdgcn_mfma_f32_16x16x32_bf16(afh, bh, accV[ng * 4 + nt], 0, 0, 0);
                }
        }
        __syncthreads();
    }

    // epilogue: C/D layout col=lane&15, row=4*(lane>>4)+reg
    const int col = lane & 15;
    const int rg  = (lane >> 4) * 4;
#pragma unroll
    for (int ng = 0; ng < 2; ++ng)
#pragma unroll
        for (int nt = 0; nt < 4; ++nt) {
            const int n = wn + ng * 64 + nt * 16 + col;
            const float biasY = uf[n];
            const float biasV = bv[n];
            const int m = m0 + wm + rg;
#pragma unroll
            for (int r = 0; r < 4; ++r) {
                Ypt[(size_t)(m + r) * C_DIM + n] = accK[ng * 4 + nt][r] + biasY;
                Vtb[(size_t)(m + r) * C_DIM + n] = bf16_rne(accV[ng * 4 + nt][r] + biasV);
            }
        }
}

// ---------------------------------------------------------------------------
// attn (idx fused): per pixel -- finalize offsets from part (f64, identical
// association order to the proven idx_kernel), round -> idx; then
// logit_n = Yp_pix . x_gather[idx_n]  (vq term dropped: softmax-invariant);
// softmax; V-sum (bf16 gather); transposed store.
// ---------------------------------------------------------------------------
__global__ __launch_bounds__(1024) void attn_kernel(
    const double* __restrict__ part,
    const double* __restrict__ beff,
    const float* __restrict__ Ypt,
    const u16*   __restrict__ xh,
    const u16*   __restrict__ xl,
    const u16*   __restrict__ Vtb,
    float* __restrict__ out)
{
    __shared__ float trans[16][260];

    const int t    = threadIdx.x;
    const int wave = t >> 6;
    const int lane = t & 63;

    const int pix0 = blockIdx.x * 16;
    const int b    = pix0 / HW_DIM;
    const int hw   = (pix0 % HW_DIM) + wave;
    const int pix  = b * HW_DIM + hw;
    const int h    = hw >> 6;
    const int w    = hw & 63;

    // ---- idx finalize on lanes 0..7 (exact r11 numerics) ----
    float oval = 0.0f;
    if (lane < 8) {
        const double o = part[(size_t)(0 * NPJ + lane) * NPIX + pix]
                       + part[(size_t)(1 * NPJ + lane) * NPIX + pix]
                       + part[(size_t)(2 * NPJ + lane) * NPIX + pix]
                       + part[(size_t)(3 * NPJ + lane) * NPIX + pix]
                       + beff[lane];
        oval = (float)o;
    }
    int idx[NREF];
#pragma unroll
    for (int n = 0; n < NREF; ++n) {
        const float ox = __shfl(oval, 2 * n);
        const float oy = __shfl(oval, 2 * n + 1);
        int rx = (int)rintf((float)w + ox);
        int ry = (int)rintf((float)h + oy);
        rx = min(max(rx, 0), W_DIM - 1);
        ry = min(max(ry, 0), H_DIM - 1);
        idx[n] = ry * W_DIM + rx;
    }

    // ---- query row (coalesced f32) ----
    float y[4];
    *(float4*)y = *(const float4*)(Ypt + (size_t)pix * C_DIM + lane * 4);

    // ---- logits: y . x_g (x gathered as exact hi+lo bf16 planes) ----
    float logit[NREF];
#pragma unroll
    for (int n = 0; n < NREF; ++n) {
        const size_t g = ((size_t)b * HW_DIM + idx[n]) * C_DIM + lane * 4;
        const u16x4 gh = *(const u16x4*)(xh + g);
        const u16x4 gl = *(const u16x4*)(xl + g);
        float lp = 0.0f;
#pragma unroll
        for (int i = 0; i < 4; ++i)
            lp = fmaf(y[i], bf16_tof(gh[i]) + bf16_tof(gl[i]), lp);
#pragma unroll
        for (int off = 1; off < 64; off <<= 1) lp += __shfl_xor(lp, off);
        logit[n] = lp;
    }

    float mx = fmaxf(fmaxf(logit[0], logit[1]), fmaxf(logit[2], logit[3]));
    float e[NREF], s = 0.0f;
#pragma unroll
    for (int n = 0; n < NREF; ++n) { e[n] = expf(logit[n] - mx); s += e[n]; }
    float wgt[NREF];
#pragma unroll
    for (int n = 0; n < NREF; ++n) wgt[n] = e[n] / s;

    float o4[4] = {0.f, 0.f, 0.f, 0.f};
#pragma unroll
    for (int n = 0; n < NREF; ++n) {
        const u16x4 vv = *(const u16x4*)(Vtb + ((size_t)b * HW_DIM + idx[n]) * C_DIM + lane * 4);
        o4[0] = fmaf(wgt[n], bf16_tof(vv[0]), o4[0]);
        o4[1] = fmaf(wgt[n], bf16_tof(vv[1]), o4[1]);
        o4[2] = fmaf(wgt[n], bf16_tof(vv[2]), o4[2]);
        o4[3] = fmaf(wgt[n], bf16_tof(vv[3]), o4[3]);
    }

    *(float4*)&trans[wave][lane * 4] = *(float4*)o4;
    __syncthreads();

    float* ob = out + (size_t)b * C_DIM * HW_DIM + (pix0 % HW_DIM);
    const int px = t & 15;
#pragma unroll
    for (int cc = 0; cc < C_DIM; cc += 64) {
        const int c = cc + (t >> 4);
        ob[(size_t)c * HW_DIM + px] = trans[px][c];
    }
}

// ---------------------------------------------------------------------------
extern "C" void kernel_launch(void* const* d_in, const int* in_sizes, int n_in,
                              void* d_out, int out_size, void* d_ws, size_t ws_size,
                              hipStream_t stream) {
    const float* x    = (const float*)d_in[0];
    const float* Wq   = (const float*)d_in[1];
    const float* bq   = (const float*)d_in[2];
    const float* Wk   = (const float*)d_in[3];
    const float* bk   = (const float*)d_in[4];
    const float* Wv   = (const float*)d_in[5];
    const float* bv   = (const float*)d_in[6];
    const float* Woff = (const float*)d_in[7];
    const float* boff = (const float*)d_in[8];
    float* out = (float*)d_out;

    // Workspace layout (~72 MiB of 256 MiB):
    //   [0,16M)   Ypt f32 (B*HW, C)
    //   [16,24M)  Vtb bf16
    //   [48,56M)  xh bf16
    //   [56,64M)  xl bf16
    //   aux = 64M:
    //     +0      Weffp f64 (4q x NJW x 256) = 72 KB
    //     +128K   beff f64 (8)
    //     +192K   uf f32 (256) = 1 KB
    //     +576K   Bswh u16 (16 tiles x 8192) = 256 KB
    //     +832K   Bswl u16 = 256 KB
    //     +2M     part f64 (4q x NPJ x NPIX) = 4.2 MB
    char* ws = (char*)d_ws;
    float*  Ypt   = (float*)ws;
    u16*    Vtb   = (u16*)  (ws + (size_t)16 * 1024 * 1024);
    u16*    xh    = (u16*)  (ws + (size_t)48 * 1024 * 1024);
    u16*    xl    = (u16*)  (ws + (size_t)56 * 1024 * 1024);
    char*   aux   = ws + (size_t)64 * 1024 * 1024;
    double* Weffp = (double*)(aux);
    double* beff  = (double*)(aux + 128 * 1024);
    float*  uf    = (float*) (aux + 192 * 1024);
    u16*    Bswh  = (u16*)   (aux + 576 * 1024);
    u16*    Bswl  = (u16*)   (aux + 832 * 1024);
    double* part  = (double*)(aux + 2 * 1024 * 1024);

    // 1) GEMV rows (index path) + Mt f32 GEMM + W images
    prep_kernel<<<dim3(76), dim3(256), 0, stream>>>(
        Wq, bq, Wk, bk, Wv, Woff, boff, Weffp, beff, Bswh, Bswl);
    // 2) transpose+split x, per-pixel GEMV partials, u finalize
    xsplit_kernel<<<dim3(HW_DIM / 64, C_DIM / 64, B_DIM), dim3(256), 0, stream>>>(
        x, Weffp, xh, xl, part, uf);
    // 3) merged Yp (3-pass, f32+u bias) + V (1-pass, bf16) MFMA
    qkv_mfma<<<dim3(NPIX / 32), dim3(256), 0, stream>>>(
        xh, xl, Bswh, Bswl, uf, bv, Ypt, Vtb);
    // 4) fused idx + gather-attention
    attn_kernel<<<dim3(NPIX / 16), dim3(1024), 0, stream>>>(
        part, beff, Ypt, xh, xl, Vtb, out);
}